// Round 6
// baseline (169.675 us; speedup 1.0000x reference)
//
#include <hip/hip_runtime.h>

namespace {

// 2-point Gauss-Legendre nodes on [0,1], weights 0.5 each.
constexpr double G1 = 0.21132486540518712;
constexpr double G2 = 0.78867513459481288;

__host__ __device__ constexpr double qd(int j, double t) {
    if (j == 0) return 1.0/6.0 - 0.5*t + 0.5*t*t - t*t*t/6.0;
    if (j == 1) return 2.0/3.0 - t*t + 0.5*t*t*t;
    if (j == 2) return 1.0/6.0 + 0.5*t + 0.5*t*t - 0.5*t*t*t;
    return t*t*t/6.0;
}
__host__ __device__ constexpr double qpd(int j, double t) {
    if (j == 0) return -0.5 + t - 0.5*t*t;
    if (j == 1) return -2.0*t + 1.5*t*t;
    if (j == 2) return  0.5 + t - 1.5*t*t;
    return 0.5*t*t;
}
__host__ __device__ constexpr float QG(int j, int g) { return (float)qd (j, g ? G2 : G1); }
__host__ __device__ constexpr float QP(int j, int g) { return (float)qpd(j, g ? G2 : G1); }
__host__ __device__ constexpr float Q(int j, int k)  { return (float)qd(j, k * 0.1); }
__host__ __device__ constexpr float DQ(int j, int s) { return (float)(qd(j, (s + 1) * 0.1) - qd(j, s * 0.1)); }

constexpr int BLOCK = 256;

// 0.5/(1 + 0.01*zs) via 2-term series (e in [0,0.01], |rel err| < 1.1e-6).
__device__ inline float slo_half(float zs) {
    return __fmaf_rn(zs, __fmaf_rn(zs, 5e-5f, -5e-3f), 0.5f);
}

// One interior row via 2-pt Gauss quadrature of the continuous integrand.
__device__ inline float gauss_row(float x0, float z0, float x1, float z1,
                                  float x2, float z2, float x3, float z3) {
    const float d10 = x1 - x0, d20 = x2 - x0, d30 = x3 - x0;
    const float e10 = z1 - z0, e20 = z2 - z0, e30 = z3 - z0;
    float acc = 0.0f;
    #pragma unroll
    for (int g = 0; g < 2; ++g) {
        float xp = d10 * QP(1, g);
        xp = __fmaf_rn(d20, QP(2, g), xp);
        xp = __fmaf_rn(d30, QP(3, g), xp);
        float zp = e10 * QP(1, g);
        zp = __fmaf_rn(e20, QP(2, g), zp);
        zp = __fmaf_rn(e30, QP(3, g), zp);
        float zs = z0 * QG(0, g);
        zs = __fmaf_rn(z1, QG(1, g), zs);
        zs = __fmaf_rn(z2, QG(2, g), zs);
        zs = __fmaf_rn(z3, QG(3, g), zs);
        const float spd = __builtin_amdgcn_sqrtf(__fmaf_rn(xp, xp, zp * zp));
        acc = __fmaf_rn(slo_half(zs), spd, acc);
    }
    return acc;
}

// Exact reference polyline for one clamped row (boundaries + odd leftover).
__device__ float row_contrib(const float* __restrict__ y, int i, int nknots) {
    const int i0 = max(i - 2, 0), i1 = max(i - 1, 0);
    const int i2 = min(i, nknots), i3 = min(i + 1, nknots);
    const float x0 = y[2 * i0], z0 = y[2 * i0 + 1];
    const float x1 = y[2 * i1], z1 = y[2 * i1 + 1];
    const float x2 = y[2 * i2], z2 = y[2 * i2 + 1];
    const float x3 = y[2 * i3], z3 = y[2 * i3 + 1];

    float zs[11], rch[11];
    #pragma unroll
    for (int k = 0; k < 11; ++k) {
        float v = z0 * Q(0, k);
        v = __fmaf_rn(z1, Q(1, k), v);
        v = __fmaf_rn(z2, Q(2, k), v);
        v = __fmaf_rn(z3, Q(3, k), v);
        zs[k]  = v;
        rch[k] = slo_half(v);
    }
    const float d10 = x1 - x0, d20 = x2 - x0, d30 = x3 - x0;
    float acc = 0.0f;
    #pragma unroll
    for (int s = 0; s < 10; ++s) {
        float dx = d10 * DQ(1, s);
        dx = __fmaf_rn(d20, DQ(2, s), dx);
        dx = __fmaf_rn(d30, DQ(3, s), dx);
        const float dz = zs[s + 1] - zs[s];
        const float dist = __builtin_amdgcn_sqrtf(__fmaf_rn(dx, dx, dz * dz));
        acc = __fmaf_rn(rch[s] + rch[s + 1], dist, acc);
    }
    return acc;
}

// Single fused kernel. Thread t handles interior rows 2+2t and 3+2t.
// Knot window: y2[2t .. 2t+4] = two aligned float4 + one float2.
// Last-arriving block folds the per-block partials + boundary rows.
__global__ __launch_bounds__(BLOCK) void raybend_fused(
    const float4* __restrict__ y4, int pairs, int leftover, int nknots,
    float* __restrict__ partial, unsigned int* __restrict__ counter,
    float* __restrict__ out) {
    const int t = blockIdx.x * BLOCK + threadIdx.x;
    float acc = 0.0f;

    if (t < pairs) {
        const float4 a = y4[t];          // knots 2t, 2t+1
        const float4 b = y4[t + 1];      // knots 2t+2, 2t+3
        const float4 c = y4[t + 2];      // knots 2t+4 (xy used)
        // row 2+2t: knots 2t .. 2t+3
        acc  = gauss_row(a.x, a.y, a.z, a.w, b.x, b.y, b.z, b.w);
        // row 3+2t: knots 2t+1 .. 2t+4
        acc += gauss_row(a.z, a.w, b.x, b.y, b.z, b.w, c.x, c.y);
    }

    // Block reduce.
    #pragma unroll
    for (int off = 32; off > 0; off >>= 1) acc += __shfl_down(acc, off, 64);
    __shared__ float wsum[BLOCK / 64];
    if ((threadIdx.x & 63) == 0) wsum[threadIdx.x >> 6] = acc;
    __syncthreads();

    __shared__ bool is_last;
    if (threadIdx.x == 0) {
        float tsum = 0.0f;
        #pragma unroll
        for (int w = 0; w < BLOCK / 64; ++w) tsum += wsum[w];
        __hip_atomic_store(&partial[blockIdx.x], tsum, __ATOMIC_RELAXED,
                           __HIP_MEMORY_SCOPE_AGENT);
        __threadfence();  // release: partial visible device-wide
        const unsigned int old = atomicAdd(counter, 1u);
        is_last = (old == gridDim.x - 1);
    }
    __syncthreads();

    if (is_last) {
        __threadfence();  // acquire
        float a = 0.0f;
        for (int k = threadIdx.x; k < (int)gridDim.x; k += BLOCK)
            a += __hip_atomic_load(&partial[k], __ATOMIC_RELAXED,
                                   __HIP_MEMORY_SCOPE_AGENT);
        // Boundary rows (exact polyline) + odd leftover interior row.
        const float* y = (const float*)y4;
        if ((int)threadIdx.x < 4 + leftover) {
            const int td = threadIdx.x;
            const int row = (td < 2) ? td
                          : (td < 4) ? nknots + (td - 2)
                          : nknots - 1;  // leftover interior row (2+2*pairs)
            acc = row_contrib(y, row, nknots);
            a += acc;
        }
        #pragma unroll
        for (int off = 32; off > 0; off >>= 1) a += __shfl_down(a, off, 64);
        __shared__ float fsum[BLOCK / 64];
        if ((threadIdx.x & 63) == 0) fsum[threadIdx.x >> 6] = a;
        __syncthreads();
        if (threadIdx.x == 0) {
            float tsum = 0.0f;
            #pragma unroll
            for (int w = 0; w < BLOCK / 64; ++w) tsum += fsum[w];
            out[0] = tsum;
        }
    }
}

} // namespace

extern "C" void kernel_launch(void* const* d_in, const int* in_sizes, int n_in,
                              void* d_out, int out_size, void* d_ws, size_t ws_size,
                              hipStream_t stream) {
    const float* y = (const float*)d_in[0];
    const int nknots = in_sizes[0] / 2 - 1;
    int n_interior = nknots - 2;
    if (n_interior < 0) n_interior = 0;
    const int pairs    = n_interior >> 1;
    const int leftover = n_interior - 2 * pairs;   // 0 or 1 (row nknots-1)

    int grid = (pairs + BLOCK - 1) / BLOCK;
    if (grid < 1) grid = 1;

    unsigned int* counter = (unsigned int*)d_ws;            // 4 B at offset 0
    float* partial = (float*)((char*)d_ws + 256);           // grid floats

    hipMemsetAsync(counter, 0, sizeof(unsigned int), stream);
    raybend_fused<<<grid, BLOCK, 0, stream>>>(
        (const float4*)y, pairs, leftover, nknots, partial, counter, (float*)d_out);
}

// Round 7
// 38.633 us; speedup vs baseline: 4.3919x; 4.3919x over previous
//
#include <hip/hip_runtime.h>

namespace {

// 2-point Gauss-Legendre nodes on [0,1], weights 0.5 each.
constexpr double G1 = 0.21132486540518712;
constexpr double G2 = 0.78867513459481288;

__host__ __device__ constexpr double qd(int j, double t) {
    if (j == 0) return 1.0/6.0 - 0.5*t + 0.5*t*t - t*t*t/6.0;
    if (j == 1) return 2.0/3.0 - t*t + 0.5*t*t*t;
    if (j == 2) return 1.0/6.0 + 0.5*t + 0.5*t*t - 0.5*t*t*t;
    return t*t*t/6.0;
}
__host__ __device__ constexpr double qpd(int j, double t) {
    if (j == 0) return -0.5 + t - 0.5*t*t;
    if (j == 1) return -2.0*t + 1.5*t*t;
    if (j == 2) return  0.5 + t - 1.5*t*t;
    return 0.5*t*t;
}
__host__ __device__ constexpr float QG(int j, int g) { return (float)qd (j, g ? G2 : G1); }
__host__ __device__ constexpr float QP(int j, int g) { return (float)qpd(j, g ? G2 : G1); }
__host__ __device__ constexpr float Q(int j, int k)  { return (float)qd(j, k * 0.1); }
__host__ __device__ constexpr float DQ(int j, int s) { return (float)(qd(j, (s + 1) * 0.1) - qd(j, s * 0.1)); }

constexpr int BLOCK = 256;
constexpr int RPT   = 8;   // interior rows per thread

// 0.5/(1 + 0.01*zs) via 2-term series (e in [0,0.01], |rel err| < 1.1e-6).
__device__ inline float slo_half(float zs) {
    return __fmaf_rn(zs, __fmaf_rn(zs, 5e-5f, -5e-3f), 0.5f);
}

// One interior row via 2-pt Gauss quadrature of the continuous integrand.
__device__ inline float gauss_row(float x0, float z0, float x1, float z1,
                                  float x2, float z2, float x3, float z3) {
    const float d10 = x1 - x0, d20 = x2 - x0, d30 = x3 - x0;
    const float e10 = z1 - z0, e20 = z2 - z0, e30 = z3 - z0;
    float acc = 0.0f;
    #pragma unroll
    for (int g = 0; g < 2; ++g) {
        float xp = d10 * QP(1, g);
        xp = __fmaf_rn(d20, QP(2, g), xp);
        xp = __fmaf_rn(d30, QP(3, g), xp);
        float zp = e10 * QP(1, g);
        zp = __fmaf_rn(e20, QP(2, g), zp);
        zp = __fmaf_rn(e30, QP(3, g), zp);
        float zs = z0 * QG(0, g);
        zs = __fmaf_rn(z1, QG(1, g), zs);
        zs = __fmaf_rn(z2, QG(2, g), zs);
        zs = __fmaf_rn(z3, QG(3, g), zs);
        const float spd = __builtin_amdgcn_sqrtf(__fmaf_rn(xp, xp, zp * zp));
        acc = __fmaf_rn(slo_half(zs), spd, acc);
    }
    return acc;
}

// Exact reference polyline for one clamped row (boundaries + ragged tail).
__device__ float row_contrib(const float* __restrict__ y, int i, int nknots) {
    const int i0 = max(i - 2, 0), i1 = max(i - 1, 0);
    const int i2 = min(i, nknots), i3 = min(i + 1, nknots);
    const float x0 = y[2 * i0], z0 = y[2 * i0 + 1];
    const float x1 = y[2 * i1], z1 = y[2 * i1 + 1];
    const float x2 = y[2 * i2], z2 = y[2 * i2 + 1];
    const float x3 = y[2 * i3], z3 = y[2 * i3 + 1];

    float zs[11], rch[11];
    #pragma unroll
    for (int k = 0; k < 11; ++k) {
        float v = z0 * Q(0, k);
        v = __fmaf_rn(z1, Q(1, k), v);
        v = __fmaf_rn(z2, Q(2, k), v);
        v = __fmaf_rn(z3, Q(3, k), v);
        zs[k]  = v;
        rch[k] = slo_half(v);
    }
    const float d10 = x1 - x0, d20 = x2 - x0, d30 = x3 - x0;
    float acc = 0.0f;
    #pragma unroll
    for (int s = 0; s < 10; ++s) {
        float dx = d10 * DQ(1, s);
        dx = __fmaf_rn(d20, DQ(2, s), dx);
        dx = __fmaf_rn(d30, DQ(3, s), dx);
        const float dz = zs[s + 1] - zs[s];
        const float dist = __builtin_amdgcn_sqrtf(__fmaf_rn(dx, dx, dz * dz));
        acc = __fmaf_rn(rch[s] + rch[s + 1], dist, acc);
    }
    return acc;
}

// Single kernel. Thread t handles interior rows 2+8t .. 9+8t.
// Knot window 8t..8t+10: five aligned float4 + one float2. One device-scope
// atomicAdd per block (single instruction, writes through to the coherent
// point — NO __threadfence, which costs an L2 writeback per call on gfx950).
__global__ __launch_bounds__(BLOCK) void raybend_one(
    const float4* __restrict__ y4, const float2* __restrict__ y2,
    int chunks, int leftover, int nknots, float* __restrict__ out) {
    const int t = blockIdx.x * BLOCK + threadIdx.x;
    float acc = 0.0f;

    if (t < chunks) {
        float kx[11], kz[11];
        #pragma unroll
        for (int q = 0; q < 5; ++q) {
            const float4 v = y4[4 * t + q];      // knots 8t+2q, 8t+2q+1
            kx[2 * q + 0] = v.x; kz[2 * q + 0] = v.y;
            kx[2 * q + 1] = v.z; kz[2 * q + 1] = v.w;
        }
        {
            const float2 v = y2[8 * t + 10];     // knot 8t+10
            kx[10] = v.x; kz[10] = v.y;
        }
        #pragma unroll
        for (int j = 0; j < RPT; ++j)
            acc += gauss_row(kx[j], kz[j], kx[j + 1], kz[j + 1],
                             kx[j + 2], kz[j + 2], kx[j + 3], kz[j + 3]);
    }

    // Block 0: boundary rows (exact polyline) + ragged-tail interior rows.
    if (blockIdx.x == 0) {
        const int td = threadIdx.x;
        const float* y = (const float*)y2;
        if (td < 4) {
            const int row = (td < 2) ? td : nknots + (td - 2);
            acc += row_contrib(y, row, nknots);
        } else if (td < 4 + leftover) {
            acc += row_contrib(y, 2 + RPT * chunks + (td - 4), nknots);
        }
    }

    // Block reduce: wave shuffle + cross-wave LDS.
    #pragma unroll
    for (int off = 32; off > 0; off >>= 1) acc += __shfl_down(acc, off, 64);
    __shared__ float wsum[BLOCK / 64];
    if ((threadIdx.x & 63) == 0) wsum[threadIdx.x >> 6] = acc;
    __syncthreads();
    if (threadIdx.x == 0) {
        float tsum = 0.0f;
        #pragma unroll
        for (int w = 0; w < BLOCK / 64; ++w) tsum += wsum[w];
        atomicAdd(out, tsum);   // device-scope, cross-XCD safe (m20)
    }
}

} // namespace

extern "C" void kernel_launch(void* const* d_in, const int* in_sizes, int n_in,
                              void* d_out, int out_size, void* d_ws, size_t ws_size,
                              hipStream_t stream) {
    const float* y = (const float*)d_in[0];
    const int nknots = in_sizes[0] / 2 - 1;
    int n_interior = nknots - 2;
    if (n_interior < 0) n_interior = 0;
    const int chunks   = n_interior / RPT;
    const int leftover = n_interior - RPT * chunks;   // 0..7

    int grid = (chunks + BLOCK - 1) / BLOCK;          // 2048 at nknots=4.19M
    if (grid < 1) grid = 1;

    hipMemsetAsync(d_out, 0, sizeof(float), stream);  // out accumulates via atomics
    raybend_one<<<grid, BLOCK, 0, stream>>>(
        (const float4*)y, (const float2*)y, chunks, leftover, nknots, (float*)d_out);
}

// Round 8
// 13.512 us; speedup vs baseline: 12.5571x; 2.8591x over previous
//
#include <hip/hip_runtime.h>

namespace {

// 2-point Gauss-Legendre nodes on [0,1], weights 0.5 each.
constexpr double G1 = 0.21132486540518712;
constexpr double G2 = 0.78867513459481288;

__host__ __device__ constexpr double qd(int j, double t) {
    if (j == 0) return 1.0/6.0 - 0.5*t + 0.5*t*t - t*t*t/6.0;
    if (j == 1) return 2.0/3.0 - t*t + 0.5*t*t*t;
    if (j == 2) return 1.0/6.0 + 0.5*t + 0.5*t*t - 0.5*t*t*t;
    return t*t*t/6.0;
}
__host__ __device__ constexpr double qpd(int j, double t) {
    if (j == 0) return -0.5 + t - 0.5*t*t;
    if (j == 1) return -2.0*t + 1.5*t*t;
    if (j == 2) return  0.5 + t - 1.5*t*t;
    return 0.5*t*t;
}
__host__ __device__ constexpr float QG(int j, int g) { return (float)qd (j, g ? G2 : G1); }
__host__ __device__ constexpr float QP(int j, int g) { return (float)qpd(j, g ? G2 : G1); }
__host__ __device__ constexpr float Q(int j, int k)  { return (float)qd(j, k * 0.1); }
__host__ __device__ constexpr float DQ(int j, int s) { return (float)(qd(j, (s + 1) * 0.1) - qd(j, s * 0.1)); }

constexpr int BLOCK = 256;
constexpr int RPT   = 8;   // interior rows per thread

// 0.5/(1 + 0.01*zs) via 2-term series (e in [0,0.01], |rel err| < 1.1e-6).
__device__ inline float slo_half(float zs) {
    return __fmaf_rn(zs, __fmaf_rn(zs, 5e-5f, -5e-3f), 0.5f);
}

// One interior row via 2-pt Gauss quadrature of the continuous integrand.
__device__ inline float gauss_row(float x0, float z0, float x1, float z1,
                                  float x2, float z2, float x3, float z3) {
    const float d10 = x1 - x0, d20 = x2 - x0, d30 = x3 - x0;
    const float e10 = z1 - z0, e20 = z2 - z0, e30 = z3 - z0;
    float acc = 0.0f;
    #pragma unroll
    for (int g = 0; g < 2; ++g) {
        float xp = d10 * QP(1, g);
        xp = __fmaf_rn(d20, QP(2, g), xp);
        xp = __fmaf_rn(d30, QP(3, g), xp);
        float zp = e10 * QP(1, g);
        zp = __fmaf_rn(e20, QP(2, g), zp);
        zp = __fmaf_rn(e30, QP(3, g), zp);
        float zs = z0 * QG(0, g);
        zs = __fmaf_rn(z1, QG(1, g), zs);
        zs = __fmaf_rn(z2, QG(2, g), zs);
        zs = __fmaf_rn(z3, QG(3, g), zs);
        const float spd = __builtin_amdgcn_sqrtf(__fmaf_rn(xp, xp, zp * zp));
        acc = __fmaf_rn(slo_half(zs), spd, acc);
    }
    return acc;
}

// Exact reference polyline for one clamped row (boundaries + ragged tail).
__device__ float row_contrib(const float* __restrict__ y, int i, int nknots) {
    const int i0 = max(i - 2, 0), i1 = max(i - 1, 0);
    const int i2 = min(i, nknots), i3 = min(i + 1, nknots);
    const float x0 = y[2 * i0], z0 = y[2 * i0 + 1];
    const float x1 = y[2 * i1], z1 = y[2 * i1 + 1];
    const float x2 = y[2 * i2], z2 = y[2 * i2 + 1];
    const float x3 = y[2 * i3], z3 = y[2 * i3 + 1];

    float zs[11], rch[11];
    #pragma unroll
    for (int k = 0; k < 11; ++k) {
        float v = z0 * Q(0, k);
        v = __fmaf_rn(z1, Q(1, k), v);
        v = __fmaf_rn(z2, Q(2, k), v);
        v = __fmaf_rn(z3, Q(3, k), v);
        zs[k]  = v;
        rch[k] = slo_half(v);
    }
    const float d10 = x1 - x0, d20 = x2 - x0, d30 = x3 - x0;
    float acc = 0.0f;
    #pragma unroll
    for (int s = 0; s < 10; ++s) {
        float dx = d10 * DQ(1, s);
        dx = __fmaf_rn(d20, DQ(2, s), dx);
        dx = __fmaf_rn(d30, DQ(3, s), dx);
        const float dz = zs[s + 1] - zs[s];
        const float dist = __builtin_amdgcn_sqrtf(__fmaf_rn(dx, dx, dz * dz));
        acc = __fmaf_rn(rch[s] + rch[s + 1], dist, acc);
    }
    return acc;
}

// Main: thread t handles interior rows 2+8t .. 9+8t. Knot window 8t..8t+10
// = five aligned float4 + one float2. Plain per-block partial store — no
// atomics (same-address RMWs serialize ~15ns each: R7's 30us tail), no
// fences (device fence = L2 writeback on gfx950: R6's 200us disaster).
__global__ __launch_bounds__(BLOCK) void raybend_main2(
    const float4* __restrict__ y4, const float2* __restrict__ y2,
    int chunks, float* __restrict__ partial) {
    const int t = blockIdx.x * BLOCK + threadIdx.x;
    float acc = 0.0f;

    if (t < chunks) {
        float kx[11], kz[11];
        #pragma unroll
        for (int q = 0; q < 5; ++q) {
            const float4 v = y4[4 * t + q];      // knots 8t+2q, 8t+2q+1
            kx[2 * q + 0] = v.x; kz[2 * q + 0] = v.y;
            kx[2 * q + 1] = v.z; kz[2 * q + 1] = v.w;
        }
        {
            const float2 v = y2[8 * t + 10];     // knot 8t+10
            kx[10] = v.x; kz[10] = v.y;
        }
        #pragma unroll
        for (int j = 0; j < RPT; ++j)
            acc += gauss_row(kx[j], kz[j], kx[j + 1], kz[j + 1],
                             kx[j + 2], kz[j + 2], kx[j + 3], kz[j + 3]);
    }

    // Block reduce: wave shuffle + cross-wave LDS.
    #pragma unroll
    for (int off = 32; off > 0; off >>= 1) acc += __shfl_down(acc, off, 64);
    __shared__ float wsum[BLOCK / 64];
    if ((threadIdx.x & 63) == 0) wsum[threadIdx.x >> 6] = acc;
    __syncthreads();
    if (threadIdx.x == 0) {
        float tsum = 0.0f;
        #pragma unroll
        for (int w = 0; w < BLOCK / 64; ++w) tsum += wsum[w];
        partial[blockIdx.x] = tsum;
    }
}

// Final: one block folds nblocks partials (float4 reads) + boundary rows
// (exact polyline) + ragged-tail interior rows.
__global__ __launch_bounds__(BLOCK) void raybend_final2(
    const float4* __restrict__ partial4, int n4,
    const float* __restrict__ y, int nknots, int tail_base, int leftover,
    float* __restrict__ out) {
    float acc = 0.0f;
    for (int k = threadIdx.x; k < n4; k += BLOCK) {
        const float4 v = partial4[k];
        acc += (v.x + v.y) + (v.z + v.w);
    }
    const int td = threadIdx.x;
    if (td < 4 + leftover) {
        const int row = (td < 2) ? td
                      : (td < 4) ? nknots + (td - 2)
                      : tail_base + (td - 4);
        acc += row_contrib(y, row, nknots);
    }

    #pragma unroll
    for (int off = 32; off > 0; off >>= 1) acc += __shfl_down(acc, off, 64);
    __shared__ float wsum[BLOCK / 64];
    if ((threadIdx.x & 63) == 0) wsum[threadIdx.x >> 6] = acc;
    __syncthreads();
    if (threadIdx.x == 0) {
        float tsum = 0.0f;
        #pragma unroll
        for (int w = 0; w < BLOCK / 64; ++w) tsum += wsum[w];
        out[0] = tsum;
    }
}

} // namespace

extern "C" void kernel_launch(void* const* d_in, const int* in_sizes, int n_in,
                              void* d_out, int out_size, void* d_ws, size_t ws_size,
                              hipStream_t stream) {
    const float* y = (const float*)d_in[0];
    const int nknots = in_sizes[0] / 2 - 1;
    int n_interior = nknots - 2;
    if (n_interior < 0) n_interior = 0;
    const int chunks    = n_interior / RPT;
    const int leftover  = n_interior - RPT * chunks;   // 0..7
    const int tail_base = 2 + RPT * chunks;

    int grid = (chunks + BLOCK - 1) / BLOCK;           // 2048 at nknots=4.19M
    if (grid < 1) grid = 1;
    int grid4 = (grid + 3) & ~3;                       // float4-aligned partial count
    if ((size_t)grid4 * sizeof(float) > ws_size) { grid = 1; grid4 = 4; }

    float* partial = (float*)d_ws;

    raybend_main2<<<grid, BLOCK, 0, stream>>>(
        (const float4*)y, (const float2*)y, chunks, partial);
    if (grid4 != grid)
        hipMemsetAsync(partial + grid, 0, (size_t)(grid4 - grid) * sizeof(float), stream);
    raybend_final2<<<1, BLOCK, 0, stream>>>(
        (const float4*)partial, grid4 / 4, y, nknots, tail_base, leftover, (float*)d_out);
}